// Round 15
// baseline (729.995 us; speedup 1.0000x reference)
//
#include <hip/hip_runtime.h>
#include <hip/hip_cooperative_groups.h>

namespace cg = cooperative_groups;

#define N_NODES 16384
#define N_EDGES 524288

typedef short bf16x8 __attribute__((ext_vector_type(8)));
typedef float f32x4 __attribute__((ext_vector_type(4)));

__device__ __forceinline__ ushort f2bf(float a) {
    uint u = __float_as_uint(a);
    return (ushort)((u + 0x7fff + ((u >> 16) & 1)) >> 16);
}
__device__ __forceinline__ uint pack2bf(float a, float b) {
    return (uint)f2bf(a) | ((uint)f2bf(b) << 16);
}
__device__ __forceinline__ float bflo(uint v) { return __uint_as_float(v << 16); }
__device__ __forceinline__ float bfhi(uint v) { return __uint_as_float(v & 0xffff0000u); }

// =====================================================================
// Cooperative front-end: zero+wT | hist | scan(parallel) | scatter+cvt | agg
// grid MUST be 1024 blocks x 256 threads (co-resident: 4 blocks/CU).
// =====================================================================
__global__ __launch_bounds__(256, 4) void fused_front(
        const int* __restrict__ src, const int* __restrict__ dst,
        const float* __restrict__ x, const float* __restrict__ W_emb,
        const float* __restrict__ W_asn, int* __restrict__ count,
        int* __restrict__ indptr, int* __restrict__ cursor,
        float* __restrict__ dinv, int* __restrict__ blocksum,
        int* __restrict__ blockoff, int* __restrict__ sorted_src,
        ushort* __restrict__ wT, ushort* __restrict__ x_bf,
        uint2* __restrict__ agg2) {
    cg::grid_group grid = cg::this_grid();
    __shared__ int part[256];
    int t = threadIdx.x;
    int tid = blockIdx.x * 256 + t;            // 0 .. 262143

    // ---- P0: zero count (4096 uint4) + pack W^T (32768 bf16) ----
    if (tid < 4096) ((uint4*)count)[tid] = make_uint4(0, 0, 0, 0);
    if (tid < 32768) {
        int k = tid >> 8, n = tid & 255;
        float v = n < 128 ? W_emb[k * 128 + n] : W_asn[k * 128 + (n - 128)];
        wT[(size_t)n * 128 + k] = f2bf(v);
    }
    grid.sync();

    // ---- P1: histogram of dst (2 edges/thread) ----
    atomicAdd(&count[dst[tid]], 1);
    atomicAdd(&count[dst[tid + 262144]], 1);
    grid.sync();

    // ---- P2a: block-local exclusive scan (blocks 0..63, 1 elem/thread) ----
    int myc = 0, excl = 0;
    if (blockIdx.x < 64) {
        int e = blockIdx.x * 256 + t;
        myc = count[e];
        part[t] = myc;
        __syncthreads();
        for (int off = 1; off < 256; off <<= 1) {
            int v = (t >= off) ? part[t - off] : 0;
            __syncthreads();
            part[t] += v;
            __syncthreads();
        }
        excl = part[t] - myc;                  // exclusive within block
        if (t == 255) blocksum[blockIdx.x] = part[255];
    }
    grid.sync();

    // ---- P2b: wave-scan of 64 block sums (block 0, wave 0) ----
    if (blockIdx.x == 0 && t < 64) {
        int bs = blocksum[t];
        int incl = bs;
        for (int d = 1; d < 64; d <<= 1) {
            int tmp = __shfl_up(incl, d);
            if (t >= d) incl += tmp;
        }
        blockoff[t] = incl - bs;               // exclusive
    }
    grid.sync();

    // ---- P2c: finalize indptr/cursor/dinv ----
    if (blockIdx.x < 64) {
        int e = blockIdx.x * 256 + t;
        int p = excl + blockoff[blockIdx.x];
        indptr[e] = p;
        cursor[e] = p;
        dinv[e] = rsqrtf((float)(myc + 1));
        if (blockIdx.x == 63 && t == 255) indptr[N_NODES] = N_EDGES;
    }
    grid.sync();

    // ---- P3: counting-sort scatter (2 edges/thread)
    //          + x' = x*dinv -> bf16 (2 float4/thread, 524288 total) ----
    {
        int e = tid;
        int d = dst[e];
        int p = atomicAdd(&cursor[d], 1);
        sorted_src[p] = src[e];
        e = tid + 262144;
        d = dst[e];
        p = atomicAdd(&cursor[d], 1);
        sorted_src[p] = src[e];
#pragma unroll
        for (int rep = 0; rep < 2; ++rep) {
            int i = tid + rep * 262144;        // float4 index, 0..524287
            float4 v = *(const float4*)(x + (size_t)i * 4);
            float dv = dinv[i >> 5];
            ushort4 o;
            o.x = f2bf(v.x * dv); o.y = f2bf(v.y * dv);
            o.z = f2bf(v.z * dv); o.w = f2bf(v.w * dv);
            *(ushort4*)(x_bf + (size_t)i * 4) = o;
        }
    }
    grid.sync();

    // ---- P4: agg[d,:] = (sum_{s in N(d)} x'[s,:] + x'[d,:]) * dinv[d] ----
    const uint2* __restrict__ xp2 = (const uint2*)x_bf;
    int w = tid >> 6;                          // global wave id, 0..4095
    int lane = t & 63;
    int half = lane >> 5, hl = lane & 31;
    for (int d = w; d < N_NODES; d += 4096) {
        int beg = indptr[d], end = indptr[d + 1];
        float a0 = 0.f, a1 = 0.f, a2 = 0.f, a3 = 0.f;
        for (int ch = beg; ch < end; ch += 64) {
            int take = end - ch; if (take > 64) take = 64;
            int myi = sorted_src[ch + (lane < take ? lane : 0)];
            int i = 0;
            for (; i + 8 <= take; i += 8) {
                int s0 = __shfl(myi, i + half);
                int s1 = __shfl(myi, i + 2 + half);
                int s2 = __shfl(myi, i + 4 + half);
                int s3 = __shfl(myi, i + 6 + half);
                uint2 v0 = xp2[(size_t)s0 * 32 + hl];
                uint2 v1 = xp2[(size_t)s1 * 32 + hl];
                uint2 v2 = xp2[(size_t)s2 * 32 + hl];
                uint2 v3 = xp2[(size_t)s3 * 32 + hl];
                a0 += (bflo(v0.x) + bflo(v1.x)) + (bflo(v2.x) + bflo(v3.x));
                a1 += (bfhi(v0.x) + bfhi(v1.x)) + (bfhi(v2.x) + bfhi(v3.x));
                a2 += (bflo(v0.y) + bflo(v1.y)) + (bflo(v2.y) + bflo(v3.y));
                a3 += (bfhi(v0.y) + bfhi(v1.y)) + (bfhi(v2.y) + bfhi(v3.y));
            }
            for (; i + 2 <= take; i += 2) {
                int s = __shfl(myi, i + half);
                uint2 v = xp2[(size_t)s * 32 + hl];
                a0 += bflo(v.x); a1 += bfhi(v.x); a2 += bflo(v.y); a3 += bfhi(v.y);
            }
            if (i < take) {
                int s = __shfl(myi, i);
                if (half == 0) {
                    uint2 v = xp2[(size_t)s * 32 + hl];
                    a0 += bflo(v.x); a1 += bfhi(v.x); a2 += bflo(v.y); a3 += bfhi(v.y);
                }
            }
        }
        a0 += __shfl_xor(a0, 32); a1 += __shfl_xor(a1, 32);
        a2 += __shfl_xor(a2, 32); a3 += __shfl_xor(a3, 32);
        if (half == 0) {
            uint2 vd = xp2[(size_t)d * 32 + hl];
            a0 += bflo(vd.x); a1 += bfhi(vd.x); a2 += bflo(vd.y); a3 += bfhi(vd.y);
            float di = dinv[d];
            uint2 o; o.x = pack2bf(a0 * di, a1 * di); o.y = pack2bf(a2 * di, a3 * di);
            agg2[(size_t)d * 32 + hl] = o;
        }
    }
}

// ---- fused GEMM + epilogue (relu->xe_T, softmax->S_out/S_bf/S_T) -----------
__global__ __launch_bounds__(512) void gemm_fused_mfma(
        const ushort* __restrict__ agg, const ushort* __restrict__ wT,
        const float* __restrict__ b_emb, const float* __restrict__ b_asn,
        float* __restrict__ S_out, uint* __restrict__ S_bf,
        ushort* __restrict__ xe_T, ushort* __restrict__ S_T) {
    __shared__ float hs[64][257];
    int l = threadIdx.x & 63, w = threadIdx.x >> 6;
    int lrow0 = (w >> 2) * 32;
    int m0 = blockIdx.x * 64 + lrow0;
    int n0 = (w & 3) * 64;
    int lr = l & 15, lk = (l >> 4) * 8;
    f32x4 acc[2][4] = {};
#pragma unroll
    for (int kk = 0; kk < 128; kk += 32) {
        bf16x8 a[2], b[4];
#pragma unroll
        for (int fm = 0; fm < 2; ++fm)
            a[fm] = *(const bf16x8*)(agg + (size_t)(m0 + fm * 16 + lr) * 128 + kk + lk);
#pragma unroll
        for (int fn = 0; fn < 4; ++fn)
            b[fn] = *(const bf16x8*)(wT + (size_t)(n0 + fn * 16 + lr) * 128 + kk + lk);
#pragma unroll
        for (int fm = 0; fm < 2; ++fm)
#pragma unroll
            for (int fn = 0; fn < 4; ++fn)
                acc[fm][fn] = __builtin_amdgcn_mfma_f32_16x16x32_bf16(
                    a[fm], b[fn], acc[fm][fn], 0, 0, 0);
    }
    int rbase = (l >> 4) * 4;
    const float* __restrict__ bvec = n0 < 128 ? b_emb : b_asn;
    int bcol0 = n0 & 127;
#pragma unroll
    for (int fn = 0; fn < 4; ++fn) {
        float bias = bvec[bcol0 + fn * 16 + lr];
#pragma unroll
        for (int fm = 0; fm < 2; ++fm)
#pragma unroll
            for (int r = 0; r < 4; ++r)
                hs[lrow0 + fm * 16 + rbase + r][n0 + fn * 16 + lr] = acc[fm][fn][r] + bias;
    }
    __syncthreads();
    int g = threadIdx.x >> 3, sub = threadIdx.x & 7;
    size_t grow = blockIdx.x * 64 + g;
#pragma unroll
    for (int j = 0; j < 16; ++j) {
        float a0 = fmaxf(hs[g][sub * 16 + j], 0.f);
        hs[g][sub * 16 + j] = a0;
    }
    float v[16];
#pragma unroll
    for (int j = 0; j < 16; ++j) v[j] = hs[g][128 + sub * 16 + j];
    float m = v[0];
#pragma unroll
    for (int j = 1; j < 16; ++j) m = fmaxf(m, v[j]);
    m = fmaxf(m, __shfl_xor(m, 1));
    m = fmaxf(m, __shfl_xor(m, 2));
    m = fmaxf(m, __shfl_xor(m, 4));
    float s = 0.f;
#pragma unroll
    for (int j = 0; j < 16; ++j) { v[j] = __expf(v[j] - m); s += v[j]; }
    s += __shfl_xor(s, 1);
    s += __shfl_xor(s, 2);
    s += __shfl_xor(s, 4);
    float inv = 1.f / s;
    uint w8[8];
#pragma unroll
    for (int j = 0; j < 16; ++j) { v[j] *= inv; hs[g][128 + sub * 16 + j] = v[j]; }
#pragma unroll
    for (int q = 0; q < 4; ++q)
        *(float4*)(&S_out[grow * 128 + sub * 16 + 4 * q]) =
            make_float4(v[4 * q], v[4 * q + 1], v[4 * q + 2], v[4 * q + 3]);
#pragma unroll
    for (int j = 0; j < 8; ++j) w8[j] = pack2bf(v[2 * j], v[2 * j + 1]);
    *(uint4*)(&S_bf[grow * 64 + sub * 8])     = make_uint4(w8[0], w8[1], w8[2], w8[3]);
    *(uint4*)(&S_bf[grow * 64 + sub * 8 + 4]) = make_uint4(w8[4], w8[5], w8[6], w8[7]);
    __syncthreads();
    int brow = blockIdx.x * 64;
#pragma unroll
    for (int r = 0; r < 4; ++r) {
        int c = (threadIdx.x >> 3) + 64 * r;
        int oct = threadIdx.x & 7;
        uint w4[4];
#pragma unroll
        for (int q = 0; q < 4; ++q) {
            float u0 = hs[oct * 8 + 2 * q][c];
            float u1 = hs[oct * 8 + 2 * q + 1][c];
            w4[q] = pack2bf(u0, u1);
        }
        ushort* __restrict__ T = c < 128 ? xe_T : S_T;
        *(uint4*)(&T[(size_t)(c & 127) * N_NODES + brow + oct * 8]) =
            make_uint4(w4[0], w4[1], w4[2], w4[3]);
    }
}

// -------- Mt[d,:] = sum over UNIQUE srcs of S[s,:]; rotation dedup ----------
__global__ void mt_kernel(const uint2* __restrict__ Sp2, const int* __restrict__ indptr,
                          const int* __restrict__ sorted_src, uint2* __restrict__ Mt2) {
    int wv = threadIdx.x >> 6, lane = threadIdx.x & 63;
    int d = blockIdx.x * 4 + wv;
    int beg = indptr[d], end = indptr[d + 1];
    int half = lane >> 5, hl = lane & 31;
    float a0 = 0.f, a1 = 0.f, a2 = 0.f, a3 = 0.f;
    for (int ch = beg; ch < end; ch += 64) {
        int take = end - ch; if (take > 64) take = 64;
        int myv = sorted_src[ch + (lane < take ? lane : 0)];
        bool dup = false;
        for (int r = 1; r < 64; ++r) {
            int ov = __shfl(myv, (lane - r) & 63);
            if (lane >= r && lane < take && ov == myv) dup = true;
        }
        for (int pc = beg; pc < ch; pc += 64) {
            int ov = sorted_src[pc + lane];
            for (int r = 0; r < 64; ++r) {
                int u = __shfl(ov, r);
                if (lane < take && u == myv) dup = true;
            }
        }
        int fl = myv | (dup ? (int)0x80000000 : 0);
        int i = 0;
        for (; i + 8 <= take; i += 8) {
            int s0 = __shfl(fl, i + half);
            int s1 = __shfl(fl, i + 2 + half);
            int s2 = __shfl(fl, i + 4 + half);
            int s3 = __shfl(fl, i + 6 + half);
            float m0 = s0 >= 0 ? 1.f : 0.f, m1 = s1 >= 0 ? 1.f : 0.f;
            float m2 = s2 >= 0 ? 1.f : 0.f, m3 = s3 >= 0 ? 1.f : 0.f;
            uint2 v0 = Sp2[(size_t)(s0 & 16383) * 32 + hl];
            uint2 v1 = Sp2[(size_t)(s1 & 16383) * 32 + hl];
            uint2 v2 = Sp2[(size_t)(s2 & 16383) * 32 + hl];
            uint2 v3 = Sp2[(size_t)(s3 & 16383) * 32 + hl];
            a0 += (bflo(v0.x) * m0 + bflo(v1.x) * m1) + (bflo(v2.x) * m2 + bflo(v3.x) * m3);
            a1 += (bfhi(v0.x) * m0 + bfhi(v1.x) * m1) + (bfhi(v2.x) * m2 + bfhi(v3.x) * m3);
            a2 += (bflo(v0.y) * m0 + bflo(v1.y) * m1) + (bflo(v2.y) * m2 + bflo(v3.y) * m3);
            a3 += (bfhi(v0.y) * m0 + bfhi(v1.y) * m1) + (bfhi(v2.y) * m2 + bfhi(v3.y) * m3);
        }
        for (; i + 2 <= take; i += 2) {
            int s = __shfl(fl, i + half);
            if (s >= 0) {
                uint2 v = Sp2[(size_t)(s & 16383) * 32 + hl];
                a0 += bflo(v.x); a1 += bfhi(v.x); a2 += bflo(v.y); a3 += bfhi(v.y);
            }
        }
        if (i < take) {
            int s = __shfl(fl, i);
            if (half == 0 && s >= 0) {
                uint2 v = Sp2[(size_t)(s & 16383) * 32 + hl];
                a0 += bflo(v.x); a1 += bfhi(v.x); a2 += bflo(v.y); a3 += bfhi(v.y);
            }
        }
    }
    a0 += __shfl_xor(a0, 32); a1 += __shfl_xor(a1, 32);
    a2 += __shfl_xor(a2, 32); a3 += __shfl_xor(a3, 32);
    if (half == 0) {
        uint2 o; o.x = pack2bf(a0, a1); o.y = pack2bf(a2, a3);
        Mt2[(size_t)d * 32 + hl] = o;
    }
}

// ------ LDS-tiled transpose (Mt): [16384][128] bf16 -> [128][16384] ---------
__global__ __launch_bounds__(256) void transpose_kernel(
        const ushort* __restrict__ Mt_bf, ushort* __restrict__ Mt_T) {
    __shared__ ushort tile[128][130];
    int tid = threadIdx.x;
    int n0 = blockIdx.x * 128;
    for (int i = tid; i < 2048; i += 256) {
        int r = i >> 4, c8 = (i & 15) << 3;
        const uint* p = (const uint*)(Mt_bf + (size_t)(n0 + r) * 128 + c8);
        uint* t = (uint*)&tile[r][c8];
        t[0] = p[0]; t[1] = p[1]; t[2] = p[2]; t[3] = p[3];
    }
    __syncthreads();
    for (int i = tid; i < 2048; i += 256) {
        int ch = i >> 4, n8 = (i & 15) << 3;
        ushort v[8];
#pragma unroll
        for (int j = 0; j < 8; ++j) v[j] = tile[n8 + j][ch];
        uint4 o;
        o.x = (uint)v[0] | ((uint)v[1] << 16);
        o.y = (uint)v[2] | ((uint)v[3] << 16);
        o.z = (uint)v[4] | ((uint)v[5] << 16);
        o.w = (uint)v[6] | ((uint)v[7] << 16);
        *(uint4*)(Mt_T + (size_t)ch * N_NODES + n0 + n8) = o;
    }
}

// ---- stage 1 (MFMA): partial = A^T_chunk @ B_chunk, chunk=128 k ------------
__global__ __launch_bounds__(512) void pool_stage1_mfma(
        const ushort* __restrict__ S_T, const ushort* __restrict__ xe_T,
        const ushort* __restrict__ Mt_T, float* __restrict__ part) {
    const ushort* __restrict__ A = blockIdx.y ? Mt_T : S_T;
    const ushort* __restrict__ B = blockIdx.y ? S_T : xe_T;
    float* __restrict__ out = part + (size_t)blockIdx.y * (128 * 16384) +
                              (size_t)blockIdx.x * 16384;
    int l = threadIdx.x & 63, w = threadIdx.x >> 6;
    int m0 = (w >> 2) * 64;
    int n0 = (w & 3) * 32;
    int lr = l & 15, lk = (l >> 4) * 8;
    int kb = blockIdx.x * 128;
    f32x4 acc[4][2] = {};
#pragma unroll
    for (int kk = 0; kk < 128; kk += 32) {
        bf16x8 a[4], b[2];
#pragma unroll
        for (int fm = 0; fm < 4; ++fm)
            a[fm] = *(const bf16x8*)(A + (size_t)(m0 + fm * 16 + lr) * N_NODES + kb + kk + lk);
#pragma unroll
        for (int fn = 0; fn < 2; ++fn)
            b[fn] = *(const bf16x8*)(B + (size_t)(n0 + fn * 16 + lr) * N_NODES + kb + kk + lk);
#pragma unroll
        for (int fm = 0; fm < 4; ++fm)
#pragma unroll
            for (int fn = 0; fn < 2; ++fn)
                acc[fm][fn] = __builtin_amdgcn_mfma_f32_16x16x32_bf16(
                    a[fm], b[fn], acc[fm][fn], 0, 0, 0);
    }
    int rbase = (l >> 4) * 4;
#pragma unroll
    for (int fm = 0; fm < 4; ++fm)
#pragma unroll
        for (int r = 0; r < 4; ++r)
#pragma unroll
            for (int fn = 0; fn < 2; ++fn)
                out[(size_t)(m0 + fm * 16 + rbase + r) * 128 + n0 + fn * 16 + lr] =
                    acc[fm][fn][r];
}

// ---- stage 2: out[idx] = sum_p partial[p][idx] -----------------------------
__global__ void pool_reduce_kernel(const float* __restrict__ part, float* __restrict__ out) {
    int idx = blockIdx.x * 256 + threadIdx.x;
    int g = idx >> 14;
    int o = idx & 16383;
    const float* __restrict__ p = part + (size_t)g * (128 * 16384) + o;
    float s = 0.f;
#pragma unroll 8
    for (int c = 0; c < 128; ++c) s += p[(size_t)c * 16384];
    out[idx] = s;
}

extern "C" void kernel_launch(void* const* d_in, const int* in_sizes, int n_in,
                              void* d_out, int out_size, void* d_ws, size_t ws_size,
                              hipStream_t stream) {
    const int*   ei     = (const int*)d_in[1];
    const float* b_emb  = (const float*)d_in[3];
    const float* b_asn  = (const float*)d_in[5];

    float* out = (float*)d_out;
    float* S_out = out + 32768;   // outputs: x_pooled(16384), A_pooled(16384), S(N*128)

    // workspace (32 MB peak, liveness-overlapped) — same map as R13 + blocksum
    char* ws = (char*)d_ws;
    ushort* x_bf    = (ushort*)(ws + 0);
    ushort* S_T     = (ushort*)(ws + 0);
    ushort* agg     = (ushort*)(ws + 4194304);
    ushort* Mt_T    = (ushort*)(ws + 4194304);
    ushort* xe_T    = (ushort*)(ws + 8388608);
    int*    sorted  = (int*)   (ws + 12582912);
    ushort* wT      = (ushort*)(ws + 14680064);
    int*    count   = (int*)   (ws + 15204352);
    int*    indptr  = (int*)   (ws + 15269888);
    int*    cursor  = (int*)   (ws + 15400960);
    float*  dinv    = (float*) (ws + 15466496);
    int*    blocksum= (int*)   (ws + 15532032);
    int*    blockoff= (int*)   (ws + 15532544);
    uint*   S_bf    = (uint*)  (ws + 16777216);
    uint*   Mt_bf   = (uint*)  (ws + 20971520);
    float*  part    = (float*) (ws + 16777216);

    // cooperative front-end (1024 x 256, 4 blocks/CU co-resident)
    {
        const int* a_src = ei;
        const int* a_dst = ei + N_EDGES;
        const float* a_x = (const float*)d_in[0];
        const float* a_We = (const float*)d_in[2];
        const float* a_Wa = (const float*)d_in[4];
        uint2* a_agg2 = (uint2*)agg;
        void* args[] = {
            (void*)&a_src, (void*)&a_dst, (void*)&a_x, (void*)&a_We, (void*)&a_Wa,
            (void*)&count, (void*)&indptr, (void*)&cursor, (void*)&dinv,
            (void*)&blocksum, (void*)&blockoff, (void*)&sorted,
            (void*)&wT, (void*)&x_bf, (void*)&a_agg2
        };
        hipLaunchCooperativeKernel((const void*)fused_front, dim3(1024), dim3(256),
                                   args, 0, stream);
    }
    gemm_fused_mfma<<<256, 512, 0, stream>>>(agg, wT, b_emb, b_asn, S_out, S_bf, xe_T, S_T);
    mt_kernel<<<4096, 256, 0, stream>>>((const uint2*)S_bf, indptr, sorted, (uint2*)Mt_bf);
    transpose_kernel<<<128, 256, 0, stream>>>((const ushort*)Mt_bf, Mt_T);
    pool_stage1_mfma<<<dim3(128, 2), 512, 0, stream>>>(S_T, xe_T, Mt_T, part);
    pool_reduce_kernel<<<128, 256, 0, stream>>>(part, out);
}

// Round 16
// 145.697 us; speedup vs baseline: 5.0104x; 5.0104x over previous
//
#include <hip/hip_runtime.h>

#define N_NODES 16384
#define N_EDGES 524288

typedef short bf16x8 __attribute__((ext_vector_type(8)));
typedef float f32x4 __attribute__((ext_vector_type(4)));

__device__ __forceinline__ ushort f2bf(float a) {
    uint u = __float_as_uint(a);
    return (ushort)((u + 0x7fff + ((u >> 16) & 1)) >> 16);
}
__device__ __forceinline__ uint pack2bf(float a, float b) {
    return (uint)f2bf(a) | ((uint)f2bf(b) << 16);
}
__device__ __forceinline__ float bflo(uint v) { return __uint_as_float(v << 16); }
__device__ __forceinline__ float bfhi(uint v) { return __uint_as_float(v & 0xffff0000u); }

// ---- prep: zero count (blocks 0..15) + pack W^T bf16 (blocks 16..143) ------
__global__ void prep_kernel(uint4* __restrict__ count4, const float* __restrict__ W_emb,
                            const float* __restrict__ W_asn, ushort* __restrict__ wT) {
    int b = blockIdx.x;
    if (b < 16) { count4[b * 256 + threadIdx.x] = make_uint4(0, 0, 0, 0); return; }
    int idx = (b - 16) * 256 + threadIdx.x;
    int k = idx >> 8, n = idx & 255;
    float v = n < 128 ? W_emb[k * 128 + n] : W_asn[k * 128 + (n - 128)];
    wT[(size_t)n * 128 + k] = f2bf(v);
}

// ---------------- histogram of dst ------------------------------------------
__global__ void hist_kernel(const int* __restrict__ dst, int* __restrict__ count) {
    int e = blockIdx.x * 256 + threadIdx.x;
    if (e < N_EDGES) atomicAdd(&count[dst[e]], 1);
}

// -------- exclusive scan -> indptr (+ cursor), dinv. Fully coalesced --------
__global__ __launch_bounds__(256) void scan_kernel(
        const int* __restrict__ count, int* __restrict__ indptr,
        int* __restrict__ cursor, float* __restrict__ dinv) {
    __shared__ int lds[64 * 257];
    __shared__ int part[256];
    int t = threadIdx.x;
#pragma unroll 4
    for (int j = 0; j < 64; ++j) {
        int e = j * 256 + t;
        lds[(e & 63) * 257 + (e >> 6)] = count[e];
    }
    __syncthreads();
    int s = 0;
#pragma unroll
    for (int i = 0; i < 64; ++i) {
        int idx = i * 257 + t;
        int v = lds[idx];
        lds[idx] = s;
        s += v;
    }
    part[t] = s;
    __syncthreads();
    for (int off = 1; off < 256; off <<= 1) {
        int v = (t >= off) ? part[t - off] : 0;
        __syncthreads();
        part[t] += v;
        __syncthreads();
    }
    int prefix = (t == 0) ? 0 : part[t - 1];
#pragma unroll
    for (int i = 0; i < 64; ++i) lds[i * 257 + t] += prefix;
    __syncthreads();
#pragma unroll 4
    for (int j = 0; j < 64; ++j) {
        int e = j * 256 + t;
        int p = lds[(e & 63) * 257 + (e >> 6)];
        indptr[e] = p;
        cursor[e] = p;
        dinv[e] = rsqrtf((float)(count[e] + 1));
    }
    if (t == 0) indptr[N_NODES] = N_EDGES;
}

// ---- fused: counting-sort scatter (blocks <2048) + x' = x*dinv -> bf16 -----
__global__ void scatter_cvt_kernel(const int* __restrict__ src, const int* __restrict__ dst,
                                   int* __restrict__ cursor, int* __restrict__ sorted_src,
                                   const float* __restrict__ x, const float* __restrict__ dinv,
                                   ushort* __restrict__ x_bf) {
    int b = blockIdx.x;
    if (b < 2048) {
        int e = b * 256 + threadIdx.x;
        int d = dst[e];
        int p = atomicAdd(&cursor[d], 1);
        sorted_src[p] = src[e];
    } else {
        int i = (b - 2048) * 256 + threadIdx.x;
        float4 v = *(const float4*)(x + (size_t)i * 4);
        float dv = dinv[i >> 5];
        ushort4 o;
        o.x = f2bf(v.x * dv); o.y = f2bf(v.y * dv);
        o.z = f2bf(v.z * dv); o.w = f2bf(v.w * dv);
        *(ushort4*)(x_bf + (size_t)i * 4) = o;
    }
}

// ---- agg[d,:] = (sum_{s in N(d)} x'[s,:] + x'[d,:]) * dinv[d]  (bf16) ------
__global__ void agg_kernel(const uint2* __restrict__ xp2, const int* __restrict__ indptr,
                           const int* __restrict__ sorted_src, const float* __restrict__ dinv,
                           uint2* __restrict__ agg2) {
    int wv = threadIdx.x >> 6, lane = threadIdx.x & 63;
    int d = blockIdx.x * 4 + wv;
    int beg = indptr[d], end = indptr[d + 1];
    int half = lane >> 5, hl = lane & 31;
    float a0 = 0.f, a1 = 0.f, a2 = 0.f, a3 = 0.f;
    for (int ch = beg; ch < end; ch += 64) {
        int take = end - ch; if (take > 64) take = 64;
        int myi = sorted_src[ch + (lane < take ? lane : 0)];
        int i = 0;
        for (; i + 8 <= take; i += 8) {
            int s0 = __shfl(myi, i + half);
            int s1 = __shfl(myi, i + 2 + half);
            int s2 = __shfl(myi, i + 4 + half);
            int s3 = __shfl(myi, i + 6 + half);
            uint2 v0 = xp2[(size_t)s0 * 32 + hl];
            uint2 v1 = xp2[(size_t)s1 * 32 + hl];
            uint2 v2 = xp2[(size_t)s2 * 32 + hl];
            uint2 v3 = xp2[(size_t)s3 * 32 + hl];
            a0 += (bflo(v0.x) + bflo(v1.x)) + (bflo(v2.x) + bflo(v3.x));
            a1 += (bfhi(v0.x) + bfhi(v1.x)) + (bfhi(v2.x) + bfhi(v3.x));
            a2 += (bflo(v0.y) + bflo(v1.y)) + (bflo(v2.y) + bflo(v3.y));
            a3 += (bfhi(v0.y) + bfhi(v1.y)) + (bfhi(v2.y) + bfhi(v3.y));
        }
        for (; i + 2 <= take; i += 2) {
            int s = __shfl(myi, i + half);
            uint2 v = xp2[(size_t)s * 32 + hl];
            a0 += bflo(v.x); a1 += bfhi(v.x); a2 += bflo(v.y); a3 += bfhi(v.y);
        }
        if (i < take) {
            int s = __shfl(myi, i);
            if (half == 0) {
                uint2 v = xp2[(size_t)s * 32 + hl];
                a0 += bflo(v.x); a1 += bfhi(v.x); a2 += bflo(v.y); a3 += bfhi(v.y);
            }
        }
    }
    a0 += __shfl_xor(a0, 32); a1 += __shfl_xor(a1, 32);
    a2 += __shfl_xor(a2, 32); a3 += __shfl_xor(a3, 32);
    if (half == 0) {
        uint2 vd = xp2[(size_t)d * 32 + hl];
        a0 += bflo(vd.x); a1 += bfhi(vd.x); a2 += bflo(vd.y); a3 += bfhi(vd.y);
        float di = dinv[d];
        uint2 o; o.x = pack2bf(a0 * di, a1 * di); o.y = pack2bf(a2 * di, a3 * di);
        agg2[(size_t)d * 32 + hl] = o;
    }
}

// ---- fused GEMM + epilogue (relu->xe_T, softmax->S_out/S_bf/S_T) -----------
__global__ __launch_bounds__(512) void gemm_fused_mfma(
        const ushort* __restrict__ agg, const ushort* __restrict__ wT,
        const float* __restrict__ b_emb, const float* __restrict__ b_asn,
        float* __restrict__ S_out, uint* __restrict__ S_bf,
        ushort* __restrict__ xe_T, ushort* __restrict__ S_T) {
    __shared__ float hs[64][257];
    int l = threadIdx.x & 63, w = threadIdx.x >> 6;
    int lrow0 = (w >> 2) * 32;
    int m0 = blockIdx.x * 64 + lrow0;
    int n0 = (w & 3) * 64;
    int lr = l & 15, lk = (l >> 4) * 8;
    f32x4 acc[2][4] = {};
#pragma unroll
    for (int kk = 0; kk < 128; kk += 32) {
        bf16x8 a[2], b[4];
#pragma unroll
        for (int fm = 0; fm < 2; ++fm)
            a[fm] = *(const bf16x8*)(agg + (size_t)(m0 + fm * 16 + lr) * 128 + kk + lk);
#pragma unroll
        for (int fn = 0; fn < 4; ++fn)
            b[fn] = *(const bf16x8*)(wT + (size_t)(n0 + fn * 16 + lr) * 128 + kk + lk);
#pragma unroll
        for (int fm = 0; fm < 2; ++fm)
#pragma unroll
            for (int fn = 0; fn < 4; ++fn)
                acc[fm][fn] = __builtin_amdgcn_mfma_f32_16x16x32_bf16(
                    a[fm], b[fn], acc[fm][fn], 0, 0, 0);
    }
    int rbase = (l >> 4) * 4;
    const float* __restrict__ bvec = n0 < 128 ? b_emb : b_asn;
    int bcol0 = n0 & 127;
#pragma unroll
    for (int fn = 0; fn < 4; ++fn) {
        float bias = bvec[bcol0 + fn * 16 + lr];
#pragma unroll
        for (int fm = 0; fm < 2; ++fm)
#pragma unroll
            for (int r = 0; r < 4; ++r)
                hs[lrow0 + fm * 16 + rbase + r][n0 + fn * 16 + lr] = acc[fm][fn][r] + bias;
    }
    __syncthreads();
    int g = threadIdx.x >> 3, sub = threadIdx.x & 7;
    size_t grow = blockIdx.x * 64 + g;
#pragma unroll
    for (int j = 0; j < 16; ++j) {
        float a0 = fmaxf(hs[g][sub * 16 + j], 0.f);
        hs[g][sub * 16 + j] = a0;
    }
    float v[16];
#pragma unroll
    for (int j = 0; j < 16; ++j) v[j] = hs[g][128 + sub * 16 + j];
    float m = v[0];
#pragma unroll
    for (int j = 1; j < 16; ++j) m = fmaxf(m, v[j]);
    m = fmaxf(m, __shfl_xor(m, 1));
    m = fmaxf(m, __shfl_xor(m, 2));
    m = fmaxf(m, __shfl_xor(m, 4));
    float s = 0.f;
#pragma unroll
    for (int j = 0; j < 16; ++j) { v[j] = __expf(v[j] - m); s += v[j]; }
    s += __shfl_xor(s, 1);
    s += __shfl_xor(s, 2);
    s += __shfl_xor(s, 4);
    float inv = 1.f / s;
    uint w8[8];
#pragma unroll
    for (int j = 0; j < 16; ++j) { v[j] *= inv; hs[g][128 + sub * 16 + j] = v[j]; }
#pragma unroll
    for (int q = 0; q < 4; ++q)
        *(float4*)(&S_out[grow * 128 + sub * 16 + 4 * q]) =
            make_float4(v[4 * q], v[4 * q + 1], v[4 * q + 2], v[4 * q + 3]);
#pragma unroll
    for (int j = 0; j < 8; ++j) w8[j] = pack2bf(v[2 * j], v[2 * j + 1]);
    *(uint4*)(&S_bf[grow * 64 + sub * 8])     = make_uint4(w8[0], w8[1], w8[2], w8[3]);
    *(uint4*)(&S_bf[grow * 64 + sub * 8 + 4]) = make_uint4(w8[4], w8[5], w8[6], w8[7]);
    __syncthreads();
    int brow = blockIdx.x * 64;
#pragma unroll
    for (int r = 0; r < 4; ++r) {
        int c = (threadIdx.x >> 3) + 64 * r;
        int oct = threadIdx.x & 7;
        uint w4[4];
#pragma unroll
        for (int q = 0; q < 4; ++q) {
            float u0 = hs[oct * 8 + 2 * q][c];
            float u1 = hs[oct * 8 + 2 * q + 1][c];
            w4[q] = pack2bf(u0, u1);
        }
        ushort* __restrict__ T = c < 128 ? xe_T : S_T;
        *(uint4*)(&T[(size_t)(c & 127) * N_NODES + brow + oct * 8]) =
            make_uint4(w4[0], w4[1], w4[2], w4[3]);
    }
}

// -------- Mt[d,:] = sum over UNIQUE srcs of S[s,:]; rotation dedup ----------
__global__ void mt_kernel(const uint2* __restrict__ Sp2, const int* __restrict__ indptr,
                          const int* __restrict__ sorted_src, uint2* __restrict__ Mt2) {
    int wv = threadIdx.x >> 6, lane = threadIdx.x & 63;
    int d = blockIdx.x * 4 + wv;
    int beg = indptr[d], end = indptr[d + 1];
    int half = lane >> 5, hl = lane & 31;
    float a0 = 0.f, a1 = 0.f, a2 = 0.f, a3 = 0.f;
    for (int ch = beg; ch < end; ch += 64) {
        int take = end - ch; if (take > 64) take = 64;
        int myv = sorted_src[ch + (lane < take ? lane : 0)];
        bool dup = false;
        for (int r = 1; r < 64; ++r) {
            int ov = __shfl(myv, (lane - r) & 63);
            if (lane >= r && lane < take && ov == myv) dup = true;
        }
        for (int pc = beg; pc < ch; pc += 64) {
            int ov = sorted_src[pc + lane];
            for (int r = 0; r < 64; ++r) {
                int u = __shfl(ov, r);
                if (lane < take && u == myv) dup = true;
            }
        }
        int fl = myv | (dup ? (int)0x80000000 : 0);
        int i = 0;
        for (; i + 8 <= take; i += 8) {
            int s0 = __shfl(fl, i + half);
            int s1 = __shfl(fl, i + 2 + half);
            int s2 = __shfl(fl, i + 4 + half);
            int s3 = __shfl(fl, i + 6 + half);
            float m0 = s0 >= 0 ? 1.f : 0.f, m1 = s1 >= 0 ? 1.f : 0.f;
            float m2 = s2 >= 0 ? 1.f : 0.f, m3 = s3 >= 0 ? 1.f : 0.f;
            uint2 v0 = Sp2[(size_t)(s0 & 16383) * 32 + hl];
            uint2 v1 = Sp2[(size_t)(s1 & 16383) * 32 + hl];
            uint2 v2 = Sp2[(size_t)(s2 & 16383) * 32 + hl];
            uint2 v3 = Sp2[(size_t)(s3 & 16383) * 32 + hl];
            a0 += (bflo(v0.x) * m0 + bflo(v1.x) * m1) + (bflo(v2.x) * m2 + bflo(v3.x) * m3);
            a1 += (bfhi(v0.x) * m0 + bfhi(v1.x) * m1) + (bfhi(v2.x) * m2 + bfhi(v3.x) * m3);
            a2 += (bflo(v0.y) * m0 + bflo(v1.y) * m1) + (bflo(v2.y) * m2 + bflo(v3.y) * m3);
            a3 += (bfhi(v0.y) * m0 + bfhi(v1.y) * m1) + (bfhi(v2.y) * m2 + bfhi(v3.y) * m3);
        }
        for (; i + 2 <= take; i += 2) {
            int s = __shfl(fl, i + half);
            if (s >= 0) {
                uint2 v = Sp2[(size_t)(s & 16383) * 32 + hl];
                a0 += bflo(v.x); a1 += bfhi(v.x); a2 += bflo(v.y); a3 += bfhi(v.y);
            }
        }
        if (i < take) {
            int s = __shfl(fl, i);
            if (half == 0 && s >= 0) {
                uint2 v = Sp2[(size_t)(s & 16383) * 32 + hl];
                a0 += bflo(v.x); a1 += bfhi(v.x); a2 += bflo(v.y); a3 += bfhi(v.y);
            }
        }
    }
    a0 += __shfl_xor(a0, 32); a1 += __shfl_xor(a1, 32);
    a2 += __shfl_xor(a2, 32); a3 += __shfl_xor(a3, 32);
    if (half == 0) {
        uint2 o; o.x = pack2bf(a0, a1); o.y = pack2bf(a2, a3);
        Mt2[(size_t)d * 32 + hl] = o;
    }
}

// ------ LDS-tiled transpose (Mt): [16384][128] bf16 -> [128][16384] ---------
__global__ __launch_bounds__(256) void transpose_kernel(
        const ushort* __restrict__ Mt_bf, ushort* __restrict__ Mt_T) {
    __shared__ ushort tile[128][130];
    int tid = threadIdx.x;
    int n0 = blockIdx.x * 128;
    for (int i = tid; i < 2048; i += 256) {
        int r = i >> 4, c8 = (i & 15) << 3;
        const uint* p = (const uint*)(Mt_bf + (size_t)(n0 + r) * 128 + c8);
        uint* t = (uint*)&tile[r][c8];
        t[0] = p[0]; t[1] = p[1]; t[2] = p[2]; t[3] = p[3];
    }
    __syncthreads();
    for (int i = tid; i < 2048; i += 256) {
        int ch = i >> 4, n8 = (i & 15) << 3;
        ushort v[8];
#pragma unroll
        for (int j = 0; j < 8; ++j) v[j] = tile[n8 + j][ch];
        uint4 o;
        o.x = (uint)v[0] | ((uint)v[1] << 16);
        o.y = (uint)v[2] | ((uint)v[3] << 16);
        o.z = (uint)v[4] | ((uint)v[5] << 16);
        o.w = (uint)v[6] | ((uint)v[7] << 16);
        *(uint4*)(Mt_T + (size_t)ch * N_NODES + n0 + n8) = o;
    }
}

// ---- stage 1 (MFMA): partial = A^T_chunk @ B_chunk, chunk=128 k ------------
__global__ __launch_bounds__(512) void pool_stage1_mfma(
        const ushort* __restrict__ S_T, const ushort* __restrict__ xe_T,
        const ushort* __restrict__ Mt_T, float* __restrict__ part) {
    const ushort* __restrict__ A = blockIdx.y ? Mt_T : S_T;
    const ushort* __restrict__ B = blockIdx.y ? S_T : xe_T;
    float* __restrict__ out = part + (size_t)blockIdx.y * (128 * 16384) +
                              (size_t)blockIdx.x * 16384;
    int l = threadIdx.x & 63, w = threadIdx.x >> 6;
    int m0 = (w >> 2) * 64;
    int n0 = (w & 3) * 32;
    int lr = l & 15, lk = (l >> 4) * 8;
    int kb = blockIdx.x * 128;
    f32x4 acc[4][2] = {};
#pragma unroll
    for (int kk = 0; kk < 128; kk += 32) {
        bf16x8 a[4], b[2];
#pragma unroll
        for (int fm = 0; fm < 4; ++fm)
            a[fm] = *(const bf16x8*)(A + (size_t)(m0 + fm * 16 + lr) * N_NODES + kb + kk + lk);
#pragma unroll
        for (int fn = 0; fn < 2; ++fn)
            b[fn] = *(const bf16x8*)(B + (size_t)(n0 + fn * 16 + lr) * N_NODES + kb + kk + lk);
#pragma unroll
        for (int fm = 0; fm < 4; ++fm)
#pragma unroll
            for (int fn = 0; fn < 2; ++fn)
                acc[fm][fn] = __builtin_amdgcn_mfma_f32_16x16x32_bf16(
                    a[fm], b[fn], acc[fm][fn], 0, 0, 0);
    }
    int rbase = (l >> 4) * 4;
#pragma unroll
    for (int fm = 0; fm < 4; ++fm)
#pragma unroll
        for (int r = 0; r < 4; ++r)
#pragma unroll
            for (int fn = 0; fn < 2; ++fn)
                out[(size_t)(m0 + fm * 16 + rbase + r) * 128 + n0 + fn * 16 + lr] =
                    acc[fm][fn][r];
}

// ---- stage 2: out[idx] = sum_p partial[p][idx] -----------------------------
__global__ void pool_reduce_kernel(const float* __restrict__ part, float* __restrict__ out) {
    int idx = blockIdx.x * 256 + threadIdx.x;
    int g = idx >> 14;
    int o = idx & 16383;
    const float* __restrict__ p = part + (size_t)g * (128 * 16384) + o;
    float s = 0.f;
#pragma unroll 8
    for (int c = 0; c < 128; ++c) s += p[(size_t)c * 16384];
    out[idx] = s;
}

extern "C" void kernel_launch(void* const* d_in, const int* in_sizes, int n_in,
                              void* d_out, int out_size, void* d_ws, size_t ws_size,
                              hipStream_t stream) {
    const float* x      = (const float*)d_in[0];
    const int*   ei     = (const int*)d_in[1];
    const float* W_emb  = (const float*)d_in[2];
    const float* b_emb  = (const float*)d_in[3];
    const float* W_asn  = (const float*)d_in[4];
    const float* b_asn  = (const float*)d_in[5];
    const int* src = ei;
    const int* dst = ei + N_EDGES;

    float* out = (float*)d_out;
    float* S_out = out + 32768;   // outputs: x_pooled(16384), A_pooled(16384), S(N*128)

    // workspace (32 MB peak, liveness-overlapped):
    //  [0,4M)    x_bf (cvt->agg), then S_T (gemm->stage1)
    //  [4,8M)    agg (agg->gemm), then Mt_T (transpose->stage1)
    //  [8,12M)   xe_T (gemm->stage1)
    //  [12,14M)  sorted
    //  [14M,16M) wT, count, indptr, cursor, dinv
    //  [16,20M)  S_bf (gemm->mt), [20,24M) Mt_bf (mt->transpose)
    //  [16,32M)  part (stage1->reduce; S_bf/Mt_bf dead)
    char* ws = (char*)d_ws;
    ushort* x_bf    = (ushort*)(ws + 0);
    ushort* S_T     = (ushort*)(ws + 0);
    ushort* agg     = (ushort*)(ws + 4194304);
    ushort* Mt_T    = (ushort*)(ws + 4194304);
    ushort* xe_T    = (ushort*)(ws + 8388608);
    int*    sorted  = (int*)   (ws + 12582912);
    ushort* wT      = (ushort*)(ws + 14680064);
    int*    count   = (int*)   (ws + 15204352);
    int*    indptr  = (int*)   (ws + 15269888);
    int*    cursor  = (int*)   (ws + 15400960);
    float*  dinv    = (float*) (ws + 15466496);
    uint*   S_bf    = (uint*)  (ws + 16777216);
    uint*   Mt_bf   = (uint*)  (ws + 20971520);
    float*  part    = (float*) (ws + 16777216);

    prep_kernel<<<144, 256, 0, stream>>>((uint4*)count, W_emb, W_asn, wT);
    hist_kernel<<<2048, 256, 0, stream>>>(dst, count);
    scan_kernel<<<1, 256, 0, stream>>>(count, indptr, cursor, dinv);
    scatter_cvt_kernel<<<4096, 256, 0, stream>>>(src, dst, cursor, sorted, x, dinv, x_bf);
    agg_kernel<<<4096, 256, 0, stream>>>((const uint2*)x_bf, indptr, sorted, dinv,
                                         (uint2*)agg);
    gemm_fused_mfma<<<256, 512, 0, stream>>>(agg, wT, b_emb, b_asn, S_out, S_bf, xe_T, S_T);
    mt_kernel<<<4096, 256, 0, stream>>>((const uint2*)S_bf, indptr, sorted, (uint2*)Mt_bf);
    transpose_kernel<<<128, 256, 0, stream>>>((const ushort*)Mt_bf, Mt_T);
    pool_stage1_mfma<<<dim3(128, 2), 512, 0, stream>>>(S_T, xe_T, Mt_T, part);
    pool_reduce_kernel<<<128, 256, 0, stream>>>(part, out);
}

// Round 17
// 140.598 us; speedup vs baseline: 5.1921x; 1.0363x over previous
//
#include <hip/hip_runtime.h>

#define N_NODES 16384
#define N_EDGES 524288

typedef short bf16x8 __attribute__((ext_vector_type(8)));
typedef float f32x4 __attribute__((ext_vector_type(4)));

__device__ __forceinline__ ushort f2bf(float a) {
    uint u = __float_as_uint(a);
    return (ushort)((u + 0x7fff + ((u >> 16) & 1)) >> 16);
}
__device__ __forceinline__ uint pack2bf(float a, float b) {
    return (uint)f2bf(a) | ((uint)f2bf(b) << 16);
}
__device__ __forceinline__ float bflo(uint v) { return __uint_as_float(v << 16); }
__device__ __forceinline__ float bfhi(uint v) { return __uint_as_float(v & 0xffff0000u); }

// ---- prep: zero count (blocks 0..15) + pack W^T bf16 (blocks 16..143) ------
__global__ void prep_kernel(uint4* __restrict__ count4, const float* __restrict__ W_emb,
                            const float* __restrict__ W_asn, ushort* __restrict__ wT) {
    int b = blockIdx.x;
    if (b < 16) { count4[b * 256 + threadIdx.x] = make_uint4(0, 0, 0, 0); return; }
    int idx = (b - 16) * 256 + threadIdx.x;
    int k = idx >> 8, n = idx & 255;
    float v = n < 128 ? W_emb[k * 128 + n] : W_asn[k * 128 + (n - 128)];
    wT[(size_t)n * 128 + k] = f2bf(v);
}

// ---------------- histogram of dst ------------------------------------------
__global__ void hist_kernel(const int* __restrict__ dst, int* __restrict__ count) {
    int e = blockIdx.x * 256 + threadIdx.x;
    if (e < N_EDGES) atomicAdd(&count[dst[e]], 1);
}

// -------- exclusive scan -> indptr (+ cursor), dinv. 1024 thr, wave scans ---
// element e = q*16+i lives at lds[i*1041 + q]  (1041: bank-conflict-free)
__global__ __launch_bounds__(1024) void scan_kernel(
        const int* __restrict__ count, int* __restrict__ indptr,
        int* __restrict__ cursor, float* __restrict__ dinv) {
    __shared__ int lds[16 * 1041];
    __shared__ int wsum[16];
    int t = threadIdx.x;
#pragma unroll
    for (int j = 0; j < 16; ++j) {               // coalesced read, transposed store
        int e = j * 1024 + t;
        lds[(t & 15) * 1041 + j * 64 + (t >> 4)] = count[e];
    }
    __syncthreads();
    int s = 0;                                   // serial scan of own 16 elems
#pragma unroll
    for (int i = 0; i < 16; ++i) {
        int idx = i * 1041 + t;
        int v = lds[idx];
        lds[idx] = s;
        s += v;
    }
    int lane = t & 63, wid = t >> 6;
    int incl = s;                                // wave inclusive scan
    for (int d = 1; d < 64; d <<= 1) {
        int tmp = __shfl_up(incl, d);
        if (lane >= d) incl += tmp;
    }
    if (lane == 63) wsum[wid] = incl;
    __syncthreads();
    if (wid == 0) {                              // scan the 16 wave sums
        int v = (lane < 16) ? wsum[lane] : 0;
        int ic = v;
        for (int d = 1; d < 16; d <<= 1) {
            int tmp = __shfl_up(ic, d);
            if (lane >= d) ic += tmp;
        }
        if (lane < 16) wsum[lane] = ic - v;      // exclusive wave offset
    }
    __syncthreads();
    int base = wsum[wid] + (incl - s);           // thread's exclusive prefix
#pragma unroll
    for (int i = 0; i < 16; ++i) lds[i * 1041 + t] += base;
    __syncthreads();
#pragma unroll
    for (int j = 0; j < 16; ++j) {               // coalesced write-out
        int e = j * 1024 + t;
        int p = lds[(t & 15) * 1041 + j * 64 + (t >> 4)];
        indptr[e] = p;
        cursor[e] = p;
        dinv[e] = rsqrtf((float)(count[e] + 1));
    }
    if (t == 0) indptr[N_NODES] = N_EDGES;
}

// ---- fused: counting-sort scatter (blocks <2048) + x' = x*dinv -> bf16 -----
__global__ void scatter_cvt_kernel(const int* __restrict__ src, const int* __restrict__ dst,
                                   int* __restrict__ cursor, int* __restrict__ sorted_src,
                                   const float* __restrict__ x, const float* __restrict__ dinv,
                                   ushort* __restrict__ x_bf) {
    int b = blockIdx.x;
    if (b < 2048) {
        int e = b * 256 + threadIdx.x;
        int d = dst[e];
        int p = atomicAdd(&cursor[d], 1);
        sorted_src[p] = src[e];
    } else {
        int i = (b - 2048) * 256 + threadIdx.x;
        float4 v = *(const float4*)(x + (size_t)i * 4);
        float dv = dinv[i >> 5];
        ushort4 o;
        o.x = f2bf(v.x * dv); o.y = f2bf(v.y * dv);
        o.z = f2bf(v.z * dv); o.w = f2bf(v.w * dv);
        *(ushort4*)(x_bf + (size_t)i * 4) = o;
    }
}

// ---- agg[d,:] = (sum_{s in N(d)} x'[s,:] + x'[d,:]) * dinv[d]  (bf16) ------
__global__ void agg_kernel(const uint2* __restrict__ xp2, const int* __restrict__ indptr,
                           const int* __restrict__ sorted_src, const float* __restrict__ dinv,
                           uint2* __restrict__ agg2) {
    int wv = threadIdx.x >> 6, lane = threadIdx.x & 63;
    int d = blockIdx.x * 4 + wv;
    int beg = indptr[d], end = indptr[d + 1];
    int half = lane >> 5, hl = lane & 31;
    float a0 = 0.f, a1 = 0.f, a2 = 0.f, a3 = 0.f;
    for (int ch = beg; ch < end; ch += 64) {
        int take = end - ch; if (take > 64) take = 64;
        int myi = sorted_src[ch + (lane < take ? lane : 0)];
        int i = 0;
        for (; i + 8 <= take; i += 8) {
            int s0 = __shfl(myi, i + half);
            int s1 = __shfl(myi, i + 2 + half);
            int s2 = __shfl(myi, i + 4 + half);
            int s3 = __shfl(myi, i + 6 + half);
            uint2 v0 = xp2[(size_t)s0 * 32 + hl];
            uint2 v1 = xp2[(size_t)s1 * 32 + hl];
            uint2 v2 = xp2[(size_t)s2 * 32 + hl];
            uint2 v3 = xp2[(size_t)s3 * 32 + hl];
            a0 += (bflo(v0.x) + bflo(v1.x)) + (bflo(v2.x) + bflo(v3.x));
            a1 += (bfhi(v0.x) + bfhi(v1.x)) + (bfhi(v2.x) + bfhi(v3.x));
            a2 += (bflo(v0.y) + bflo(v1.y)) + (bflo(v2.y) + bflo(v3.y));
            a3 += (bfhi(v0.y) + bfhi(v1.y)) + (bfhi(v2.y) + bfhi(v3.y));
        }
        for (; i + 2 <= take; i += 2) {
            int s = __shfl(myi, i + half);
            uint2 v = xp2[(size_t)s * 32 + hl];
            a0 += bflo(v.x); a1 += bfhi(v.x); a2 += bflo(v.y); a3 += bfhi(v.y);
        }
        if (i < take) {
            int s = __shfl(myi, i);
            if (half == 0) {
                uint2 v = xp2[(size_t)s * 32 + hl];
                a0 += bflo(v.x); a1 += bfhi(v.x); a2 += bflo(v.y); a3 += bfhi(v.y);
            }
        }
    }
    a0 += __shfl_xor(a0, 32); a1 += __shfl_xor(a1, 32);
    a2 += __shfl_xor(a2, 32); a3 += __shfl_xor(a3, 32);
    if (half == 0) {
        uint2 vd = xp2[(size_t)d * 32 + hl];
        a0 += bflo(vd.x); a1 += bfhi(vd.x); a2 += bflo(vd.y); a3 += bfhi(vd.y);
        float di = dinv[d];
        uint2 o; o.x = pack2bf(a0 * di, a1 * di); o.y = pack2bf(a2 * di, a3 * di);
        agg2[(size_t)d * 32 + hl] = o;
    }
}

// ---- fused GEMM + epilogue (relu->xe_T, softmax->S_out/S_bf/S_T) -----------
__global__ __launch_bounds__(512) void gemm_fused_mfma(
        const ushort* __restrict__ agg, const ushort* __restrict__ wT,
        const float* __restrict__ b_emb, const float* __restrict__ b_asn,
        float* __restrict__ S_out, uint* __restrict__ S_bf,
        ushort* __restrict__ xe_T, ushort* __restrict__ S_T) {
    __shared__ float hs[64][257];
    int l = threadIdx.x & 63, w = threadIdx.x >> 6;
    int lrow0 = (w >> 2) * 32;
    int m0 = blockIdx.x * 64 + lrow0;
    int n0 = (w & 3) * 64;
    int lr = l & 15, lk = (l >> 4) * 8;
    f32x4 acc[2][4] = {};
#pragma unroll
    for (int kk = 0; kk < 128; kk += 32) {
        bf16x8 a[2], b[4];
#pragma unroll
        for (int fm = 0; fm < 2; ++fm)
            a[fm] = *(const bf16x8*)(agg + (size_t)(m0 + fm * 16 + lr) * 128 + kk + lk);
#pragma unroll
        for (int fn = 0; fn < 4; ++fn)
            b[fn] = *(const bf16x8*)(wT + (size_t)(n0 + fn * 16 + lr) * 128 + kk + lk);
#pragma unroll
        for (int fm = 0; fm < 2; ++fm)
#pragma unroll
            for (int fn = 0; fn < 4; ++fn)
                acc[fm][fn] = __builtin_amdgcn_mfma_f32_16x16x32_bf16(
                    a[fm], b[fn], acc[fm][fn], 0, 0, 0);
    }
    int rbase = (l >> 4) * 4;
    const float* __restrict__ bvec = n0 < 128 ? b_emb : b_asn;
    int bcol0 = n0 & 127;
#pragma unroll
    for (int fn = 0; fn < 4; ++fn) {
        float bias = bvec[bcol0 + fn * 16 + lr];
#pragma unroll
        for (int fm = 0; fm < 2; ++fm)
#pragma unroll
            for (int r = 0; r < 4; ++r)
                hs[lrow0 + fm * 16 + rbase + r][n0 + fn * 16 + lr] = acc[fm][fn][r] + bias;
    }
    __syncthreads();
    int g = threadIdx.x >> 3, sub = threadIdx.x & 7;
    size_t grow = blockIdx.x * 64 + g;
#pragma unroll
    for (int j = 0; j < 16; ++j) {
        float a0 = fmaxf(hs[g][sub * 16 + j], 0.f);
        hs[g][sub * 16 + j] = a0;
    }
    float v[16];
#pragma unroll
    for (int j = 0; j < 16; ++j) v[j] = hs[g][128 + sub * 16 + j];
    float m = v[0];
#pragma unroll
    for (int j = 1; j < 16; ++j) m = fmaxf(m, v[j]);
    m = fmaxf(m, __shfl_xor(m, 1));
    m = fmaxf(m, __shfl_xor(m, 2));
    m = fmaxf(m, __shfl_xor(m, 4));
    float s = 0.f;
#pragma unroll
    for (int j = 0; j < 16; ++j) { v[j] = __expf(v[j] - m); s += v[j]; }
    s += __shfl_xor(s, 1);
    s += __shfl_xor(s, 2);
    s += __shfl_xor(s, 4);
    float inv = 1.f / s;
    uint w8[8];
#pragma unroll
    for (int j = 0; j < 16; ++j) { v[j] *= inv; hs[g][128 + sub * 16 + j] = v[j]; }
#pragma unroll
    for (int q = 0; q < 4; ++q)
        *(float4*)(&S_out[grow * 128 + sub * 16 + 4 * q]) =
            make_float4(v[4 * q], v[4 * q + 1], v[4 * q + 2], v[4 * q + 3]);
#pragma unroll
    for (int j = 0; j < 8; ++j) w8[j] = pack2bf(v[2 * j], v[2 * j + 1]);
    *(uint4*)(&S_bf[grow * 64 + sub * 8])     = make_uint4(w8[0], w8[1], w8[2], w8[3]);
    *(uint4*)(&S_bf[grow * 64 + sub * 8 + 4]) = make_uint4(w8[4], w8[5], w8[6], w8[7]);
    __syncthreads();
    int brow = blockIdx.x * 64;
#pragma unroll
    for (int r = 0; r < 4; ++r) {
        int c = (threadIdx.x >> 3) + 64 * r;
        int oct = threadIdx.x & 7;
        uint w4[4];
#pragma unroll
        for (int q = 0; q < 4; ++q) {
            float u0 = hs[oct * 8 + 2 * q][c];
            float u1 = hs[oct * 8 + 2 * q + 1][c];
            w4[q] = pack2bf(u0, u1);
        }
        ushort* __restrict__ T = c < 128 ? xe_T : S_T;
        *(uint4*)(&T[(size_t)(c & 127) * N_NODES + brow + oct * 8]) =
            make_uint4(w4[0], w4[1], w4[2], w4[3]);
    }
}

// -------- Mt[d,:] = sum over UNIQUE srcs of S[s,:]; rotation dedup ----------
__global__ void mt_kernel(const uint2* __restrict__ Sp2, const int* __restrict__ indptr,
                          const int* __restrict__ sorted_src, uint2* __restrict__ Mt2) {
    int wv = threadIdx.x >> 6, lane = threadIdx.x & 63;
    int d = blockIdx.x * 4 + wv;
    int beg = indptr[d], end = indptr[d + 1];
    int half = lane >> 5, hl = lane & 31;
    float a0 = 0.f, a1 = 0.f, a2 = 0.f, a3 = 0.f;
    for (int ch = beg; ch < end; ch += 64) {
        int take = end - ch; if (take > 64) take = 64;
        int myv = sorted_src[ch + (lane < take ? lane : 0)];
        bool dup = false;
        for (int r = 1; r < 64; ++r) {
            int ov = __shfl(myv, (lane - r) & 63);
            if (lane >= r && lane < take && ov == myv) dup = true;
        }
        for (int pc = beg; pc < ch; pc += 64) {
            int ov = sorted_src[pc + lane];
            for (int r = 0; r < 64; ++r) {
                int u = __shfl(ov, r);
                if (lane < take && u == myv) dup = true;
            }
        }
        int fl = myv | (dup ? (int)0x80000000 : 0);
        int i = 0;
        for (; i + 8 <= take; i += 8) {
            int s0 = __shfl(fl, i + half);
            int s1 = __shfl(fl, i + 2 + half);
            int s2 = __shfl(fl, i + 4 + half);
            int s3 = __shfl(fl, i + 6 + half);
            float m0 = s0 >= 0 ? 1.f : 0.f, m1 = s1 >= 0 ? 1.f : 0.f;
            float m2 = s2 >= 0 ? 1.f : 0.f, m3 = s3 >= 0 ? 1.f : 0.f;
            uint2 v0 = Sp2[(size_t)(s0 & 16383) * 32 + hl];
            uint2 v1 = Sp2[(size_t)(s1 & 16383) * 32 + hl];
            uint2 v2 = Sp2[(size_t)(s2 & 16383) * 32 + hl];
            uint2 v3 = Sp2[(size_t)(s3 & 16383) * 32 + hl];
            a0 += (bflo(v0.x) * m0 + bflo(v1.x) * m1) + (bflo(v2.x) * m2 + bflo(v3.x) * m3);
            a1 += (bfhi(v0.x) * m0 + bfhi(v1.x) * m1) + (bfhi(v2.x) * m2 + bfhi(v3.x) * m3);
            a2 += (bflo(v0.y) * m0 + bflo(v1.y) * m1) + (bflo(v2.y) * m2 + bflo(v3.y) * m3);
            a3 += (bfhi(v0.y) * m0 + bfhi(v1.y) * m1) + (bfhi(v2.y) * m2 + bfhi(v3.y) * m3);
        }
        for (; i + 2 <= take; i += 2) {
            int s = __shfl(fl, i + half);
            if (s >= 0) {
                uint2 v = Sp2[(size_t)(s & 16383) * 32 + hl];
                a0 += bflo(v.x); a1 += bfhi(v.x); a2 += bflo(v.y); a3 += bfhi(v.y);
            }
        }
        if (i < take) {
            int s = __shfl(fl, i);
            if (half == 0 && s >= 0) {
                uint2 v = Sp2[(size_t)(s & 16383) * 32 + hl];
                a0 += bflo(v.x); a1 += bfhi(v.x); a2 += bflo(v.y); a3 += bfhi(v.y);
            }
        }
    }
    a0 += __shfl_xor(a0, 32); a1 += __shfl_xor(a1, 32);
    a2 += __shfl_xor(a2, 32); a3 += __shfl_xor(a3, 32);
    if (half == 0) {
        uint2 o; o.x = pack2bf(a0, a1); o.y = pack2bf(a2, a3);
        Mt2[(size_t)d * 32 + hl] = o;
    }
}

// ---- stage 1 (MFMA): 64 chunks x K=256. y=1 stages Mt via LDS transpose ----
__global__ __launch_bounds__(512) void pool_stage1_mfma(
        const ushort* __restrict__ S_T, const ushort* __restrict__ xe_T,
        const ushort* __restrict__ Mt_bf, float* __restrict__ part0,
        float* __restrict__ part1) {
    __shared__ ushort tile[128][136];          // [col(cluster)][krow], pad 136
    int l = threadIdx.x & 63, w = threadIdx.x >> 6;
    int m0 = (w >> 2) * 64;
    int n0 = (w & 3) * 32;
    int lr = l & 15, lk = (l >> 4) * 8;
    int y = blockIdx.y;
    const ushort* __restrict__ B = y ? S_T : xe_T;
    float* __restrict__ out = (y ? part1 : part0) + (size_t)blockIdx.x * 16384;
    f32x4 acc[4][2] = {};
    for (int kb2 = 0; kb2 < 2; ++kb2) {
        int kb = blockIdx.x * 256 + kb2 * 128;
        if (y) {
            __syncthreads();                   // drain readers of prev tile
            for (int cc = threadIdx.x; cc < 2048; cc += 512) {
                int row = cc >> 4;             // K-row within tile, 0..127
                int c8 = (cc & 15) << 3;       // cluster col base
                uint4 v = *(const uint4*)(Mt_bf + (size_t)(kb + row) * 128 + c8);
                ushort* pv = (ushort*)&v;
#pragma unroll
                for (int j = 0; j < 8; ++j) tile[c8 + j][row] = pv[j];
            }
            __syncthreads();
        }
#pragma unroll
        for (int kk = 0; kk < 128; kk += 32) {
            bf16x8 a[4], b[2];
            if (y) {
#pragma unroll
                for (int fm = 0; fm < 4; ++fm)
                    a[fm] = *(const bf16x8*)&tile[m0 + fm * 16 + lr][kk + lk];
            } else {
#pragma unroll
                for (int fm = 0; fm < 4; ++fm)
                    a[fm] = *(const bf16x8*)(S_T + (size_t)(m0 + fm * 16 + lr) * N_NODES
                                             + kb + kk + lk);
            }
#pragma unroll
            for (int fn = 0; fn < 2; ++fn)
                b[fn] = *(const bf16x8*)(B + (size_t)(n0 + fn * 16 + lr) * N_NODES
                                         + kb + kk + lk);
#pragma unroll
            for (int fm = 0; fm < 4; ++fm)
#pragma unroll
                for (int fn = 0; fn < 2; ++fn)
                    acc[fm][fn] = __builtin_amdgcn_mfma_f32_16x16x32_bf16(
                        a[fm], b[fn], acc[fm][fn], 0, 0, 0);
        }
    }
    int rbase = (l >> 4) * 4;
#pragma unroll
    for (int fm = 0; fm < 4; ++fm)
#pragma unroll
        for (int r = 0; r < 4; ++r)
#pragma unroll
            for (int fn = 0; fn < 2; ++fn)
                out[(size_t)(m0 + fm * 16 + rbase + r) * 128 + n0 + fn * 16 + lr] =
                    acc[fm][fn][r];
}

// ---- stage 2: out[idx] = sum over 64 chunk partials ------------------------
__global__ void pool_reduce_kernel(const float* __restrict__ part0,
                                   const float* __restrict__ part1,
                                   float* __restrict__ out) {
    int idx = blockIdx.x * 256 + threadIdx.x;   // 0..32767
    const float* __restrict__ p = (idx < 16384 ? part0 : part1) + (idx & 16383);
    float s = 0.f;
#pragma unroll 8
    for (int c = 0; c < 64; ++c) s += p[(size_t)c * 16384];
    out[idx] = s;
}

extern "C" void kernel_launch(void* const* d_in, const int* in_sizes, int n_in,
                              void* d_out, int out_size, void* d_ws, size_t ws_size,
                              hipStream_t stream) {
    const float* x      = (const float*)d_in[0];
    const int*   ei     = (const int*)d_in[1];
    const float* W_emb  = (const float*)d_in[2];
    const float* b_emb  = (const float*)d_in[3];
    const float* W_asn  = (const float*)d_in[4];
    const float* b_asn  = (const float*)d_in[5];
    const int* src = ei;
    const int* dst = ei + N_EDGES;

    float* out = (float*)d_out;
    float* S_out = out + 32768;   // outputs: x_pooled(16384), A_pooled(16384), S(N*128)

    // workspace (liveness-overlapped):
    //  [0,4M)    x_bf (cvt->agg), then S_T (gemm->stage1)
    //  [4,8M)    agg (agg->gemm), then part0 (stage1->reduce; 64x64KB = 4MB)
    //  [8,12M)   xe_T (gemm->stage1)
    //  [12,14M)  sorted
    //  [14M,16M) wT, count, indptr, cursor, dinv
    //  [16,20M)  S_bf (gemm->mt), then part1 (stage1->reduce)
    //  [20,24M)  Mt_bf (mt->stage1)
    char* ws = (char*)d_ws;
    ushort* x_bf    = (ushort*)(ws + 0);
    ushort* S_T     = (ushort*)(ws + 0);
    ushort* agg     = (ushort*)(ws + 4194304);
    float*  part0   = (float*) (ws + 4194304);
    ushort* xe_T    = (ushort*)(ws + 8388608);
    int*    sorted  = (int*)   (ws + 12582912);
    ushort* wT      = (ushort*)(ws + 14680064);
    int*    count   = (int*)   (ws + 15204352);
    int*    indptr  = (int*)   (ws + 15269888);
    int*    cursor  = (int*)   (ws + 15400960);
    float*  dinv    = (float*) (ws + 15466496);
    uint*   S_bf    = (uint*)  (ws + 16777216);
    float*  part1   = (float*) (ws + 16777216);
    uint*   Mt_bf   = (uint*)  (ws + 20971520);

    prep_kernel<<<144, 256, 0, stream>>>((uint4*)count, W_emb, W_asn, wT);
    hist_kernel<<<2048, 256, 0, stream>>>(dst, count);
    scan_kernel<<<1, 1024, 0, stream>>>(count, indptr, cursor, dinv);
    scatter_cvt_kernel<<<4096, 256, 0, stream>>>(src, dst, cursor, sorted, x, dinv, x_bf);
    agg_kernel<<<4096, 256, 0, stream>>>((const uint2*)x_bf, indptr, sorted, dinv,
                                         (uint2*)agg);
    gemm_fused_mfma<<<256, 512, 0, stream>>>(agg, wT, b_emb, b_asn, S_out, S_bf, xe_T, S_T);
    mt_kernel<<<4096, 256, 0, stream>>>((const uint2*)S_bf, indptr, sorted, (uint2*)Mt_bf);
    pool_stage1_mfma<<<dim3(64, 2), 512, 0, stream>>>(S_T, xe_T, (const ushort*)Mt_bf,
                                                      part0, part1);
    pool_reduce_kernel<<<128, 256, 0, stream>>>(part0, part1, out);
}